// Round 9
// baseline (630.231 us; speedup 1.0000x reference)
//
#include <hip/hip_runtime.h>
#include <hip/hip_bf16.h>
#include <stdint.h>

// CriticGNN: two GraphConv branches + MLP head.
// R0: aggregate AFTER the 128->16 transform (segment_sum is linear).
// R1: runtime dtype detection (bf16 vs f32 device buffers).
// R2: CSR (counting sort by dst) + gather instead of f32 atomics.
// R3: two-level bucketed counting sort (LDS histograms, burst writes).
// R6: k_head 4 lanes/node + shfl butterfly (spill structurally bounded).
// R7: k_bucket_bin block-local LDS sort -> coalesced pair writes.
// R8: FETCH=157MB on transform1 proves f32 inputs + L1/L2 thrash from strided
//     row-streaming. transform1 v2: LDS-staged x chunks (coalesced global,
//     xl[k][node] stride-260), 2 threads/node x 2 nodes/thread (W-read amortized
//     4x). gather v2: 2 lanes/node, uint4 loads (half the scattered requests).

#define F_IN 128
#define NBMAX 512   // max coarse buckets (N <= 131072)
#define BIN_CH 16
#define BIN_EDGES (256 * BIN_CH)
#define XSTR 260    // padded node-dim stride for LDS x tile

__device__ __forceinline__ float bf2f(unsigned short u) {
    union { unsigned int i; float f; } v; v.i = ((unsigned int)u) << 16; return v.f;
}
__device__ __forceinline__ float bflo(unsigned int u) {
    union { unsigned int i; float f; } v; v.i = u << 16; return v.f;
}
__device__ __forceinline__ float bfhi(unsigned int u) {
    union { unsigned int i; float f; } v; v.i = u & 0xffff0000u; return v.f;
}
__device__ __forceinline__ unsigned short f2bf(float f) {
    union { float f; unsigned int i; } v; v.f = f;
    unsigned int u = v.i;
    unsigned int r = (u + 0x7fffu + ((u >> 16) & 1u)) >> 16;  // RNE
    return (unsigned short)r;
}
__device__ __forceinline__ unsigned pack2bf(float a, float b) {
    return (unsigned)f2bf(a) | ((unsigned)f2bf(b) << 16);
}
__device__ __forceinline__ float ldf(const void* p, int isf32, size_t i) {
    return isf32 ? ((const float*)p)[i] : bf2f(((const unsigned short*)p)[i]);
}

__global__ __launch_bounds__(256) void k_detect(
    const unsigned short* __restrict__ x, int nProbe, int* __restrict__ flag)
{
    __shared__ int cnt;
    if (threadIdx.x == 0) cnt = 0;
    __syncthreads();
    int bad = 0;
    for (int i = threadIdx.x; i < nProbe; i += 256) {
        unsigned e = (x[i] >> 7) & 0xFFu;
        if (e >= 140u) bad++;
    }
    atomicAdd(&cnt, bad);
    __syncthreads();
    if (threadIdx.x == 0) *flag = (cnt > nProbe / 16) ? 1 : 0;
}

// ---------------- bucketed CSR build (both graphs via blockIdx.y) ----------------

__global__ __launch_bounds__(256) void k_zero(int* __restrict__ p, int n) {
    int i = blockIdx.x * 256 + threadIdx.x;
    if (i < n) p[i] = 0;
}

__global__ __launch_bounds__(256) void k_bucket_hist(
    const int* __restrict__ ed0, const int* __restrict__ ed1,
    int* __restrict__ cnt, int nE)
{
    const int* ed = blockIdx.y ? ed1 : ed0;
    int* c = cnt + blockIdx.y * NBMAX;
    __shared__ int h[NBMAX];
    for (int i = threadIdx.x; i < NBMAX; i += 256) h[i] = 0;
    __syncthreads();
    int stride = gridDim.x * 256;
    for (int e = blockIdx.x * 256 + threadIdx.x; e < nE; e += stride)
        atomicAdd(&h[ed[e] >> 8], 1);
    __syncthreads();
    for (int i = threadIdx.x; i < NBMAX; i += 256)
        if (h[i]) atomicAdd(&c[i], h[i]);
}

__global__ __launch_bounds__(512) void k_bucket_scan(
    const int* __restrict__ cnt, int* __restrict__ base,
    int* __restrict__ cursor, int nb)
{
    const int* c = cnt + blockIdx.x * NBMAX;
    int* ba = base + blockIdx.x * 528;
    int* cu = cursor + blockIdx.x * NBMAX;
    __shared__ int sh[512];
    int t = threadIdx.x;
    int v = (t < nb) ? c[t] : 0;
    sh[t] = v;
    __syncthreads();
    for (int off = 1; off < 512; off <<= 1) {
        int x = (t >= off) ? sh[t - off] : 0;
        __syncthreads();
        sh[t] += x;
        __syncthreads();
    }
    int excl = sh[t] - v;
    if (t < nb) { ba[t] = excl; cu[t] = excl; }
    if (t == nb - 1) ba[nb] = excl + v;
}

// bin edges into bucket-contiguous packed array via block-local LDS sort
__global__ __launch_bounds__(256) void k_bucket_bin(
    const int* __restrict__ es0, const int* __restrict__ ed0,
    const int* __restrict__ es1, const int* __restrict__ ed1,
    int* __restrict__ cursor, unsigned* __restrict__ pairs, int nE)
{
    const int* es = blockIdx.y ? es1 : es0;
    const int* ed = blockIdx.y ? ed1 : ed0;
    int* cur = cursor + blockIdx.y * NBMAX;
    unsigned* pr = pairs + (size_t)blockIdx.y * nE;

    __shared__ int h[NBMAX];
    __shared__ int lcur[NBMAX];
    __shared__ int sh[256];
    __shared__ unsigned stage[BIN_EDGES];
    __shared__ unsigned short stageB[BIN_EDGES];

    for (int i = threadIdx.x; i < NBMAX; i += 256) h[i] = 0;
    __syncthreads();
    int e0 = blockIdx.x * BIN_EDGES;
    int s[BIN_CH], d[BIN_CH];
#pragma unroll
    for (int k = 0; k < BIN_CH; ++k) {
        int e = e0 + k * 256 + threadIdx.x;
        if (e < nE) {
            s[k] = es[e]; d[k] = ed[e];
            atomicAdd(&h[d[k] >> 8], 1);
        } else d[k] = -1;
    }
    __syncthreads();
    {
        int t = threadIdx.x;
        int a = h[2 * t], b2 = h[2 * t + 1];
        sh[t] = a + b2;
        __syncthreads();
        for (int off = 1; off < 256; off <<= 1) {
            int x = (t >= off) ? sh[t - off] : 0;
            __syncthreads();
            sh[t] += x;
            __syncthreads();
        }
        int excl = sh[t] - (a + b2);
        lcur[2 * t] = excl;
        lcur[2 * t + 1] = excl + a;
    }
    __syncthreads();
    for (int b = threadIdx.x; b < NBMAX; b += 256) {
        int c = h[b];
        if (c) {
            int g = atomicAdd(&cur[b], c);
            h[b] = g - lcur[b];
        }
    }
    __syncthreads();
#pragma unroll
    for (int k = 0; k < BIN_CH; ++k) {
        if (d[k] >= 0) {
            int b = d[k] >> 8;
            int pos = atomicAdd(&lcur[b], 1);
            stage[pos] = ((unsigned)(d[k] & 255) << 24) | (unsigned)s[k];
            stageB[pos] = (unsigned short)b;
        }
    }
    __syncthreads();
    int total = nE - e0; if (total > BIN_EDGES) total = BIN_EDGES;
    for (int i = threadIdx.x; i < total; i += 256)
        pr[h[stageB[i]] + i] = stage[i];
}

__global__ __launch_bounds__(256) void k_bucket_fine(
    const unsigned* __restrict__ pairs, const int* __restrict__ base,
    int* __restrict__ row0, int* __restrict__ srcs0,
    int* __restrict__ row1, int* __restrict__ srcs1,
    int n, int nE, int nb)
{
    const unsigned* pr = pairs + (size_t)blockIdx.y * nE;
    const int* ba = base + blockIdx.y * 528;
    int* row = blockIdx.y ? row1 : row0;
    int* srcs = blockIdx.y ? srcs1 : srcs0;
    __shared__ int cnt[256], cur[256];
    int b = blockIdx.x;
    int t = threadIdx.x;
    int s0 = ba[b], s1 = ba[b + 1];
    cnt[t] = 0;
    __syncthreads();
    for (int i = s0 + t; i < s1; i += 256)
        atomicAdd(&cnt[pr[i] >> 24], 1);
    __syncthreads();
    int c = cnt[t];
    cur[t] = c;
    __syncthreads();
    for (int off = 1; off < 256; off <<= 1) {
        int x = (t >= off) ? cur[t - off] : 0;
        __syncthreads();
        cur[t] += x;
        __syncthreads();
    }
    int excl = cur[t] - c;
    __syncthreads();
    cur[t] = s0 + excl;
    int node = (b << 8) + t;
    if (node < n) row[node] = s0 + excl;
    if (b == nb - 1 && t == 0) row[n] = nE;
    __syncthreads();
    for (int i = s0 + t; i < s1; i += 256) {
        unsigned p = pr[i];
        int slot = atomicAdd(&cur[p >> 24], 1);
        srcs[slot] = (int)(p & 0xFFFFFFu);
    }
}

// ---------------- dense compute (branch via blockIdx.y + yoff) ----------------

struct TArgs { const void *x, *ws, *wn, *bias; float* acc; void* nbr; };

// acc = x @ w_self + bias (f32); nbr = x @ w_nbr (bf16x16 row, 32 B/node)
// v2: LDS-staged x in 4 chunks of 32 k-cols, transposed xl[k][node] stride 260.
// 256 nodes/block; thread = 2 nodes (r, r+128) x 16 j (jo = 0 or 16).
__global__ __launch_bounds__(256) void k_transform1(
    TArgs a0, TArgs a1, int n, int yoff, const int* __restrict__ flag)
{
    TArgs A = (blockIdx.y + yoff) ? a1 : a0;
    const int isf32 = *flag;
    __shared__ float Wl[F_IN][32];  // cols 0..15 = w_self, 16..31 = w_nbr
    __shared__ float xl[32][XSTR];  // one 32-k chunk, transposed, padded
    for (int idx = threadIdx.x; idx < F_IN * 32; idx += 256) {
        int k = idx >> 5, j = idx & 31;
        Wl[k][j] = (j < 16) ? ldf(A.ws, isf32, k * 16 + j)
                            : ldf(A.wn, isf32, k * 16 + (j - 16));
    }
    const int t = threadIdx.x;
    const int r = t & 127;
    const int jo = (t >> 7) << 4;          // 0 or 16
    const int nbase = blockIdx.x * 256;
    const int nA = nbase + r, nB = nA + 128;

    float accA[16], accB[16];
#pragma unroll
    for (int j = 0; j < 16; ++j) { accA[j] = 0.f; accB[j] = 0.f; }

    for (int c = 0; c < 4; ++c) {
        __syncthreads();
        // stage chunk c: cols [c*32, c*32+32) of 256 rows, coalesced
        if (isf32) {
            for (int i = t; i < 2048; i += 256) {
                int R = i >> 3, u = i & 7;
                int node = nbase + R;
                float4 v = (node < n)
                    ? ((const float4*)A.x)[(size_t)node * 32 + c * 8 + u]
                    : make_float4(0.f, 0.f, 0.f, 0.f);
                int k0 = u * 4;
                xl[k0 + 0][R] = v.x; xl[k0 + 1][R] = v.y;
                xl[k0 + 2][R] = v.z; xl[k0 + 3][R] = v.w;
            }
        } else {
            for (int i = t; i < 2048; i += 256) {
                int R = i >> 3, u = i & 7;
                int node = nbase + R;
                uint2 v = (node < n)
                    ? ((const uint2*)A.x)[(size_t)node * 32 + c * 8 + u]
                    : make_uint2(0u, 0u);
                int k0 = u * 4;
                xl[k0 + 0][R] = bflo(v.x); xl[k0 + 1][R] = bfhi(v.x);
                xl[k0 + 2][R] = bflo(v.y); xl[k0 + 3][R] = bfhi(v.y);
            }
        }
        __syncthreads();
        const int kg = c * 32;
#pragma unroll 8
        for (int k = 0; k < 32; ++k) {
            float xa = xl[k][r];
            float xb = xl[k][r + 128];
            const float* w = &Wl[kg + k][jo];
#pragma unroll
            for (int j = 0; j < 16; ++j) {
                accA[j] += xa * w[j];
                accB[j] += xb * w[j];
            }
        }
    }

    if (jo == 0) {  // self part + bias -> f32 acc rows
        float b[16];
#pragma unroll
        for (int j = 0; j < 16; ++j) b[j] = ldf(A.bias, isf32, j);
        if (nA < n) {
            float4* a4 = (float4*)(A.acc + (size_t)nA * 16);
#pragma unroll
            for (int q = 0; q < 4; ++q)
                a4[q] = make_float4(accA[4*q] + b[4*q], accA[4*q+1] + b[4*q+1],
                                    accA[4*q+2] + b[4*q+2], accA[4*q+3] + b[4*q+3]);
        }
        if (nB < n) {
            float4* a4 = (float4*)(A.acc + (size_t)nB * 16);
#pragma unroll
            for (int q = 0; q < 4; ++q)
                a4[q] = make_float4(accB[4*q] + b[4*q], accB[4*q+1] + b[4*q+1],
                                    accB[4*q+2] + b[4*q+2], accB[4*q+3] + b[4*q+3]);
        }
    } else {  // neighbor part -> bf16 rows (32 B)
        if (nA < n) {
            unsigned short* nrow = (unsigned short*)A.nbr + ((size_t)nA << 4);
            *(uint4*)nrow = make_uint4(pack2bf(accA[0], accA[1]), pack2bf(accA[2], accA[3]),
                                       pack2bf(accA[4], accA[5]), pack2bf(accA[6], accA[7]));
            *(uint4*)(nrow + 8) = make_uint4(pack2bf(accA[8], accA[9]), pack2bf(accA[10], accA[11]),
                                             pack2bf(accA[12], accA[13]), pack2bf(accA[14], accA[15]));
        }
        if (nB < n) {
            unsigned short* nrow = (unsigned short*)A.nbr + ((size_t)nB << 4);
            *(uint4*)nrow = make_uint4(pack2bf(accB[0], accB[1]), pack2bf(accB[2], accB[3]),
                                       pack2bf(accB[4], accB[5]), pack2bf(accB[6], accB[7]));
            *(uint4*)(nrow + 8) = make_uint4(pack2bf(accB[8], accB[9]), pack2bf(accB[10], accB[11]),
                                             pack2bf(accB[12], accB[13]), pack2bf(accB[14], accB[15]));
        }
    }
}

struct GArgs { const int *row, *srcs; const void* val; float* out; };

// out[node,0:16] (f32) = (selfmode ? out[node] : 0) + sum_{nbrs} bf16row val[s]
// v2: 2 lanes/node; each lane covers 8 bf16 (16 B uint4 load). 8-deep pipeline.
__global__ __launch_bounds__(256) void k_gather16(
    GArgs g0, GArgs g1, int n, int selfmode, int yoff)
{
    GArgs G = (blockIdx.y + yoff) ? g1 : g0;
    int t = blockIdx.x * 256 + threadIdx.x;
    int node = t >> 1;
    if (node >= n) return;
    int c = (t & 1) << 3;   // element offset (8 bf16 per lane)
    const unsigned short* vb = (const unsigned short*)G.val;
    int rs = G.row[node], re = G.row[node + 1];
    float s0 = 0.f, s1 = 0.f, s2 = 0.f, s3 = 0.f,
          s4 = 0.f, s5 = 0.f, s6 = 0.f, s7 = 0.f;
    if (selfmode) {
        const float4* o4 = (const float4*)(G.out + ((size_t)node << 4) + c);
        float4 a = o4[0], b = o4[1];
        s0 = a.x; s1 = a.y; s2 = a.z; s3 = a.w;
        s4 = b.x; s5 = b.y; s6 = b.z; s7 = b.w;
    }
    int j = rs;
    for (; j + 8 <= re; j += 8) {
        int s[8];
        uint4 v[8];
#pragma unroll
        for (int u = 0; u < 8; ++u) s[u] = G.srcs[j + u];
#pragma unroll
        for (int u = 0; u < 8; ++u)
            v[u] = *(const uint4*)(vb + (((size_t)s[u]) << 4) + c);
#pragma unroll
        for (int u = 0; u < 8; ++u) {
            s0 += bflo(v[u].x); s1 += bfhi(v[u].x);
            s2 += bflo(v[u].y); s3 += bfhi(v[u].y);
            s4 += bflo(v[u].z); s5 += bfhi(v[u].z);
            s6 += bflo(v[u].w); s7 += bfhi(v[u].w);
        }
    }
    for (; j < re; ++j) {
        uint4 v = *(const uint4*)(vb + (((size_t)G.srcs[j]) << 4) + c);
        s0 += bflo(v.x); s1 += bfhi(v.x);
        s2 += bflo(v.y); s3 += bfhi(v.y);
        s4 += bflo(v.z); s5 += bfhi(v.z);
        s6 += bflo(v.w); s7 += bfhi(v.w);
    }
    float4* o4 = (float4*)(G.out + ((size_t)node << 4) + c);
    o4[0] = make_float4(s0, s1, s2, s3);
    o4[1] = make_float4(s4, s5, s6, s7);
}

struct L2aArgs { const float* h1; void* p1; const void *w2s, *b2; int colOff; };

// p = relu(h1); mol[:,off:off+50) = p @ w2s + b2; p1 (bf16 row) for gather 2
__global__ __launch_bounds__(256) void k_layer2a(
    L2aArgs a0, L2aArgs a1, float* __restrict__ mol, int n, int yoff,
    const int* __restrict__ flag)
{
    L2aArgs A = (blockIdx.y + yoff) ? a1 : a0;
    const int isf32 = *flag;
    __shared__ float Ws[16][50];
    __shared__ float Bs[50];
    for (int idx = threadIdx.x; idx < 800; idx += 256)
        Ws[idx / 50][idx % 50] = ldf(A.w2s, isf32, idx);
    if (threadIdx.x < 50) Bs[threadIdx.x] = ldf(A.b2, isf32, threadIdx.x);
    __syncthreads();
    int node = blockIdx.x * 256 + threadIdx.x;
    if (node >= n) return;
    float p[16];
    const float4* row = (const float4*)(A.h1 + (size_t)node * 16);
#pragma unroll
    for (int t = 0; t < 4; ++t) {
        float4 v = row[t];
        p[4 * t] = fmaxf(v.x, 0.f); p[4 * t + 1] = fmaxf(v.y, 0.f);
        p[4 * t + 2] = fmaxf(v.z, 0.f); p[4 * t + 3] = fmaxf(v.w, 0.f);
    }
    unsigned short* prow = (unsigned short*)A.p1 + ((size_t)node << 4);
    *(uint4*)prow = make_uint4(pack2bf(p[0], p[1]), pack2bf(p[2], p[3]),
                               pack2bf(p[4], p[5]), pack2bf(p[6], p[7]));
    *(uint4*)(prow + 8) = make_uint4(pack2bf(p[8], p[9]), pack2bf(p[10], p[11]),
                                     pack2bf(p[12], p[13]), pack2bf(p[14], p[15]));
    float acc[50];
#pragma unroll
    for (int j = 0; j < 50; ++j) acc[j] = Bs[j];
#pragma unroll
    for (int k = 0; k < 16; ++k) {
        float pv = p[k];
#pragma unroll
        for (int j = 0; j < 50; ++j) acc[j] += pv * Ws[k][j];
    }
    float* o = mol + (size_t)node * 100 + A.colOff;
#pragma unroll
    for (int j = 0; j < 50; ++j) o[j] = acc[j];
}

struct L2bArgs { const float* agg; const void* w2n; int colOff; };

// mol[:, colOff..colOff+50) += agg @ w2n
__global__ __launch_bounds__(256) void k_layer2b(
    L2bArgs a0, L2bArgs a1, float* __restrict__ mol, int n, int yoff,
    const int* __restrict__ flag)
{
    L2bArgs A = (blockIdx.y + yoff) ? a1 : a0;
    const int isf32 = *flag;
    __shared__ float Ws[16][50];
    for (int idx = threadIdx.x; idx < 800; idx += 256)
        Ws[idx / 50][idx % 50] = ldf(A.w2n, isf32, idx);
    __syncthreads();
    int node = blockIdx.x * 256 + threadIdx.x;
    if (node >= n) return;
    float g[16];
    const float4* grow = (const float4*)(A.agg + (size_t)node * 16);
#pragma unroll
    for (int t = 0; t < 4; ++t) {
        float4 v = grow[t];
        g[4 * t] = v.x; g[4 * t + 1] = v.y; g[4 * t + 2] = v.z; g[4 * t + 3] = v.w;
    }
    float* o = mol + (size_t)node * 100 + A.colOff;
    float acc[50];
#pragma unroll
    for (int j = 0; j < 50; ++j) acc[j] = o[j];
#pragma unroll
    for (int k = 0; k < 16; ++k) {
        float gv = g[k];
#pragma unroll
        for (int j = 0; j < 50; ++j) acc[j] += gv * Ws[k][j];
    }
#pragma unroll
    for (int j = 0; j < 50; ++j) o[j] = acc[j];
}

// head: 4 lanes/node, fp[15]/lane, __shfl_xor butterfly for h[10]
__global__ __launch_bounds__(256) void k_head(
    const float* __restrict__ mol, const void* __restrict__ action,
    const void* __restrict__ w_in, const void* __restrict__ b_in,
    const void* __restrict__ w_hid, const void* __restrict__ b_hid,
    const void* __restrict__ w_out, const void* __restrict__ b_out,
    void* __restrict__ out, int n, const int* __restrict__ flag)
{
    const int isf32 = *flag;
    __shared__ float Win[100 * 60];
    __shared__ float Whid[70 * 10];
    __shared__ float Bin[60], Bhid[10], Wout[10];
    __shared__ float Bout;
    for (int idx = threadIdx.x; idx < 6000; idx += 256) Win[idx] = ldf(w_in, isf32, idx);
    for (int idx = threadIdx.x; idx < 700; idx += 256) Whid[idx] = ldf(w_hid, isf32, idx);
    if (threadIdx.x < 60) Bin[threadIdx.x] = ldf(b_in, isf32, threadIdx.x);
    if (threadIdx.x < 10) {
        Bhid[threadIdx.x] = ldf(b_hid, isf32, threadIdx.x);
        Wout[threadIdx.x] = ldf(w_out, isf32, threadIdx.x);
    }
    if (threadIdx.x == 0) Bout = ldf(b_out, isf32, 0);
    __syncthreads();
    int t = blockIdx.x * 256 + threadIdx.x;
    int node = t >> 2;
    if (node >= n) return;
    const int q = threadIdx.x & 3;
    const int jo = q * 15;

    const float4* m4 = (const float4*)(mol + (size_t)node * 100);
    float fp[15];
#pragma unroll
    for (int j = 0; j < 15; ++j) fp[j] = Bin[jo + j];
    for (int kk = 0; kk < 25; ++kk) {
        float4 v = m4[kk];
        float xs[4] = {v.x, v.y, v.z, v.w};
#pragma unroll
        for (int hh = 0; hh < 4; ++hh) {
            float m = xs[hh];
            const float* w = &Win[(kk * 4 + hh) * 60 + jo];
#pragma unroll
            for (int j = 0; j < 15; ++j) fp[j] += m * w[j];
        }
    }
    float h[10];
#pragma unroll
    for (int j = 0; j < 10; ++j) h[j] = (q == 0) ? Bhid[j] : 0.f;
#pragma unroll
    for (int k = 0; k < 15; ++k) {
        float v = fmaxf(fp[k], 0.f);
        const float* w = &Whid[(jo + k) * 10];
#pragma unroll
        for (int j = 0; j < 10; ++j) h[j] += v * w[j];
    }
#pragma unroll
    for (int j = 0; j < 10; ++j) h[j] += __shfl_xor(h[j], 1);
#pragma unroll
    for (int j = 0; j < 10; ++j) h[j] += __shfl_xor(h[j], 2);

    if (q == 0) {
#pragma unroll
        for (int k = 0; k < 10; ++k) {
            float v = ldf(action, isf32, (size_t)node * 10 + k);
            const float* w = &Whid[(60 + k) * 10];
#pragma unroll
            for (int j = 0; j < 10; ++j) h[j] += v * w[j];
        }
        float o = Bout;
#pragma unroll
        for (int j = 0; j < 10; ++j) o += fmaxf(h[j], 0.f) * Wout[j];
        if (isf32) ((float*)out)[node] = o;
        else       ((unsigned short*)out)[node] = f2bf(o);
    }
}

extern "C" void kernel_launch(void* const* d_in, const int* in_sizes, int n_in,
                              void* d_out, int out_size, void* d_ws, size_t ws_size,
                              hipStream_t stream)
{
    const void* px   = d_in[0];
    const int*  pe   = (const int*)d_in[1];
    const void* lx   = d_in[2];
    const int*  le   = (const int*)d_in[3];
    const void* act  = d_in[4];
    const void* wp1s = d_in[5];
    const void* wp1n = d_in[6];
    const void* bp1  = d_in[7];
    const void* wp2s = d_in[8];
    const void* wp2n = d_in[9];
    const void* bp2  = d_in[10];
    const void* wl1s = d_in[11];
    const void* wl1n = d_in[12];
    const void* bl1  = d_in[13];
    const void* wl2s = d_in[14];
    const void* wl2n = d_in[15];
    const void* bl2  = d_in[16];
    const void* w_in  = d_in[17];
    const void* b_in  = d_in[18];
    const void* w_hid = d_in[19];
    const void* b_hid = d_in[20];
    const void* w_out = d_in[21];
    const void* b_out = d_in[22];

    const int N = in_sizes[0] / F_IN;
    const int E = in_sizes[1] / 2;
    const int NB = (N + 255) >> 8;

    // header: flag(64) | cnt(2*512) | base(2*528) | cursor(2*512) = 3200 ints
    int* flag    = (int*)d_ws;
    int* cnt     = flag + 64;
    int* base    = cnt + 2 * NBMAX;
    int* cursorB = base + 2 * 528;
    int* rowP    = flag + 3200;
    int* srcsP   = rowP + (N + 64);
    int* rowL    = srcsP + E;
    int* srcsL   = rowL + (N + 64);
    float* dense = (float*)(srcsL + E);
    unsigned* pairs = (unsigned*)dense;   // 2E uints; dead before dense writes

    size_t head_bytes  = (size_t)(3200 + 2 * (N + 64) + 2 * E) * 4;
    size_t need_fused  = head_bytes + (size_t)164 * N * 4;
    const bool fused = (ws_size >= need_fused);

    float *accP, *accL, *mol;
    void *n1P, *n1L;
    if (fused) {
        accP = dense;                       n1P = (void*)(accP + (size_t)N * 16);
        accL = (float*)n1P + (size_t)N * 16; n1L = (void*)(accL + (size_t)N * 16);
        mol  = (float*)n1L + (size_t)N * 16;
    } else {
        accP = accL = dense;
        n1P = n1L = (void*)(dense + (size_t)N * 16);
        mol  = dense + (size_t)N * 32;
    }

    const int nb = (N + 255) / 256;
    const int gb = (N * 2 + 255) / 256;       // gather: 2 lanes/node
    const int hb = (N * 4 + 255) / 256;       // head: 4 lanes/node
    const int bb = (E + BIN_EDGES - 1) / BIN_EDGES;

    k_detect<<<1, 256, 0, stream>>>((const unsigned short*)px, 4096, flag);

    // ---- CSR build for both graphs (blockIdx.y = graph) ----
    k_zero<<<4, 256, 0, stream>>>(cnt, 2 * NBMAX);
    k_bucket_hist<<<dim3(512, 2), 256, 0, stream>>>(pe + E, le + E, cnt, E);
    k_bucket_scan<<<2, 512, 0, stream>>>(cnt, base, cursorB, NB);
    k_bucket_bin<<<dim3(bb, 2), 256, 0, stream>>>(pe, pe + E, le, le + E,
                                                  cursorB, pairs, E);
    k_bucket_fine<<<dim3(NB, 2), 256, 0, stream>>>(pairs, base, rowP, srcsP,
                                                   rowL, srcsL, N, E, NB);

    TArgs tP{px, wp1s, wp1n, bp1, accP, n1P};
    TArgs tL{lx, wl1s, wl1n, bl1, accL, n1L};
    GArgs g1P{rowP, srcsP, n1P, accP}, g1L{rowL, srcsL, n1L, accL};
    L2aArgs aP{accP, n1P, wp2s, bp2, 0}, aL{accL, n1L, wl2s, bl2, 50};
    L2bArgs bP{accP, wp2n, 0}, bL{accL, wl2n, 50};

    if (fused) {
        k_transform1<<<dim3(nb, 2), 256, 0, stream>>>(tP, tL, N, 0, flag);
        // gathers split per graph: 3.2 MB table fits one XCD L2
        k_gather16<<<gb, 256, 0, stream>>>(g1P, g1L, N, 1, 0);
        k_gather16<<<gb, 256, 0, stream>>>(g1P, g1L, N, 1, 1);
        k_layer2a<<<dim3(nb, 2), 256, 0, stream>>>(aP, aL, mol, N, 0, flag);
        k_gather16<<<gb, 256, 0, stream>>>(g1P, g1L, N, 0, 0);
        k_gather16<<<gb, 256, 0, stream>>>(g1P, g1L, N, 0, 1);
        k_layer2b<<<dim3(nb, 2), 256, 0, stream>>>(bP, bL, mol, N, 0, flag);
    } else {
        k_transform1<<<nb, 256, 0, stream>>>(tP, tL, N, 0, flag);
        k_gather16<<<gb, 256, 0, stream>>>(g1P, g1L, N, 1, 0);
        k_layer2a<<<nb, 256, 0, stream>>>(aP, aL, mol, N, 0, flag);
        k_gather16<<<gb, 256, 0, stream>>>(g1P, g1L, N, 0, 0);
        k_layer2b<<<nb, 256, 0, stream>>>(bP, bL, mol, N, 0, flag);

        k_transform1<<<nb, 256, 0, stream>>>(tP, tL, N, 1, flag);
        k_gather16<<<gb, 256, 0, stream>>>(g1P, g1L, N, 1, 1);
        k_layer2a<<<nb, 256, 0, stream>>>(aP, aL, mol, N, 1, flag);
        k_gather16<<<gb, 256, 0, stream>>>(g1P, g1L, N, 0, 1);
        k_layer2b<<<nb, 256, 0, stream>>>(bP, bL, mol, N, 1, flag);
    }

    // ---- head (4 lanes/node) ----
    k_head<<<hb, 256, 0, stream>>>(mol, act, w_in, b_in, w_hid, b_hid, w_out, b_out,
                                   d_out, N, flag);
}